// Round 11
// baseline (386.134 us; speedup 1.0000x reference)
//
#include <hip/hip_runtime.h>
#include <hip/hip_bf16.h>
#include <cstdint>

#define NN 20000
#define NE 200000
#define NG 128
#define HID 512
#define XLR_W 1024

typedef __attribute__((ext_vector_type(4))) float f32x4;
typedef __attribute__((ext_vector_type(8))) short s16x8;

__device__ __forceinline__ float bf2f(unsigned short u) {
  union { unsigned int i; float f; } v; v.i = ((unsigned int)u) << 16; return v.f;
}
__device__ __forceinline__ unsigned short f2bf(float f) {
  union { float f; unsigned int i; } v; v.f = f;
  unsigned int i = v.i + 0x7FFFu + ((v.i >> 16) & 1u);
  return (unsigned short)(i >> 16);
}
__device__ __forceinline__ float asf(unsigned int u) {
  union { unsigned int i; float f; } v; v.i = u; return v.f;
}

// ---------------- fused prep: zero deg + cast x + pack W0 + pack W1 ----------------
__global__ __launch_bounds__(256) void k_prep(const float* __restrict__ x,
                                              unsigned short* __restrict__ xb,
                                              const float* __restrict__ Wl0, const float* __restrict__ bl0,
                                              const float* __restrict__ Wr0, const float* __restrict__ br0,
                                              unsigned short* __restrict__ wt0, float* __restrict__ bcat0,
                                              const float* __restrict__ Wl1, const float* __restrict__ bl1,
                                              const float* __restrict__ Wr1, const float* __restrict__ br1,
                                              unsigned short* __restrict__ wt1, float* __restrict__ bcat1,
                                              int* __restrict__ deg) {
  int b = blockIdx.x, t = threadIdx.x;
  if (b < 79) {
    int i = b * 256 + t;
    if (i < NN) deg[i] = 0;
  } else if (b < 5079) {
    int i = (b - 79) * 256 + t;
    float4 v = ((const float4*)x)[i];
    ushort4 o;
    o.x = f2bf(v.x); o.y = f2bf(v.y); o.z = f2bf(v.z); o.w = f2bf(v.w);
    ((ushort4*)xb)[i] = o;
  } else if (b < 6103) {
    int id = (b - 5079) * 256 + t;
    int nrow = id >> 8, k = id & 255;
    float v = (nrow < HID) ? Wl0[k * HID + nrow] : Wr0[k * HID + (nrow - HID)];
    wt0[id] = f2bf(v);
    if (id < XLR_W) bcat0[id] = (id < HID) ? bl0[id] : br0[id - HID];
  } else {
    int id = (b - 6103) * 256 + t;
    int nrow = id >> 9, k = id & 511;
    float v = (nrow < HID) ? Wl1[k * HID + nrow] : Wr1[k * HID + (nrow - HID)];
    wt1[id] = f2bf(v);
    if (id < XLR_W) bcat1[id] = (id < HID) ? bl1[id] : br1[id - HID];
  }
}

// ---------------- CSR build ----------------
__global__ void k_hist(const int* __restrict__ dst, int* __restrict__ deg, int E) {
  int i = blockIdx.x * blockDim.x + threadIdx.x;
  if (i < E) atomicAdd(&deg[dst[i]], 1);
}

__global__ __launch_bounds__(1024) void k_scan1(const int* __restrict__ deg,
                                                int* __restrict__ offs,
                                                int* __restrict__ btot, int n) {
  __shared__ int wsum[16];
  int t = threadIdx.x;
  int wid = t >> 6, lane = t & 63;
  int i = blockIdx.x * 1024 + t;
  int v = (i < n) ? deg[i] : 0;
  int s = v;
#pragma unroll
  for (int off = 1; off < 64; off <<= 1) {
    int x = __shfl_up(s, off, 64);
    if (lane >= off) s += x;
  }
  if (lane == 63) wsum[wid] = s;
  __syncthreads();
  if (wid == 0) {
    int ws = (lane < 16) ? wsum[lane] : 0;
#pragma unroll
    for (int off = 1; off < 16; off <<= 1) {
      int x = __shfl_up(ws, off, 64);
      if (lane >= off) ws += x;
    }
    if (lane < 16) wsum[lane] = ws;
  }
  __syncthreads();
  int ex = s - v + (wid ? wsum[wid - 1] : 0);
  if (i < n) offs[i] = ex;
  if (t == 1023) btot[blockIdx.x] = ex + v;
}

__global__ __launch_bounds__(1024) void k_scan3(int* __restrict__ offs,
                                                const int* __restrict__ btot,
                                                int* __restrict__ woff, int n, int nb) {
  __shared__ int sbofs;
  int t = threadIdx.x;
  if (t < 64) {
    int v = (t < nb) ? btot[t] : 0;
    int s = v;
#pragma unroll
    for (int off = 1; off < 64; off <<= 1) {
      int x = __shfl_up(s, off, 64);
      if (t >= off) s += x;
    }
    if (t == (int)blockIdx.x) sbofs = s - v;
    if (blockIdx.x == (unsigned)(nb - 1) && t == nb - 1) offs[n] = s;
  }
  __syncthreads();
  int add = sbofs;
  int i = blockIdx.x * 1024 + t;
  if (i < n) {
    int v = offs[i] + add;
    offs[i] = v;
    woff[i] = v;
  }
}

__global__ void k_scatter(const int* __restrict__ src, const int* __restrict__ dst,
                          int* __restrict__ woff, int* __restrict__ src_s, int E) {
  int i = blockIdx.x * blockDim.x + threadIdx.x;
  if (i < E) {
    int d = dst[i];
    int pos = atomicAdd(&woff[d], 1);
    src_s[pos] = src[i];
  }
}

// ---------------- GEMM, LDS-free: one wave = one 64x64 C tile, frags direct global->VGPR ----------------
// No barriers, no LDS, no bank conflicts. Per K-iter: 8 dwordx4 loads + 16 MFMA.
// For fixed (i,mq) the 64 lanes cover 16 complete 64B cachelines (4 mq-chunks = 1 line).
__global__ __launch_bounds__(256) void k_gemm(const unsigned short* __restrict__ A,
                                              const unsigned short* __restrict__ Bt,
                                              const float* __restrict__ bias,
                                              unsigned short* __restrict__ C,
                                              int M, int N, int K) {
  int t = threadIdx.x;
  int wave = t >> 6, lane = t & 63;
  int wid = blockIdx.x * 4 + wave;
  int mi = wid >> 4, ni = wid & 15;      // N fixed at 1024 -> 16 n-tiles
  int m0 = mi * 64, n0 = ni * 64;
  if (m0 >= M) return;
  int ml = lane & 15, mq = lane >> 4;

  const unsigned short* pa[4];
  const unsigned short* pb[4];
#pragma unroll
  for (int i = 0; i < 4; i++) {
    int row = m0 + i * 16 + ml; if (row > M - 1) row = M - 1;
    pa[i] = A + (size_t)row * K + mq * 8;
  }
#pragma unroll
  for (int j = 0; j < 4; j++)
    pb[j] = Bt + (size_t)(n0 + j * 16 + ml) * K + mq * 8;

  f32x4 acc[4][4];
#pragma unroll
  for (int i = 0; i < 4; i++)
#pragma unroll
    for (int j = 0; j < 4; j++) acc[i][j] = (f32x4)0.0f;

  // 1-deep register pipeline
  s16x8 ac[4], bc[4], an[4], bn[4];
#pragma unroll
  for (int i = 0; i < 4; i++) { ac[i] = *(const s16x8*)pa[i]; pa[i] += 32; }
#pragma unroll
  for (int j = 0; j < 4; j++) { bc[j] = *(const s16x8*)pb[j]; pb[j] += 32; }

  int T = K >> 5;  // K/32
  for (int tt = 0; tt < T - 1; tt++) {
#pragma unroll
    for (int i = 0; i < 4; i++) { an[i] = *(const s16x8*)pa[i]; pa[i] += 32; }
#pragma unroll
    for (int j = 0; j < 4; j++) { bn[j] = *(const s16x8*)pb[j]; pb[j] += 32; }
#pragma unroll
    for (int i = 0; i < 4; i++)
#pragma unroll
      for (int j = 0; j < 4; j++)
        acc[i][j] = __builtin_amdgcn_mfma_f32_16x16x32_bf16(ac[i], bc[j], acc[i][j], 0, 0, 0);
#pragma unroll
    for (int i = 0; i < 4; i++) ac[i] = an[i];
#pragma unroll
    for (int j = 0; j < 4; j++) bc[j] = bn[j];
  }
#pragma unroll
  for (int i = 0; i < 4; i++)
#pragma unroll
    for (int j = 0; j < 4; j++)
      acc[i][j] = __builtin_amdgcn_mfma_f32_16x16x32_bf16(ac[i], bc[j], acc[i][j], 0, 0, 0);

#pragma unroll
  for (int i = 0; i < 4; i++) {
#pragma unroll
    for (int j = 0; j < 4; j++) {
      int col = n0 + j * 16 + ml;
      float bcol = bias[col];
#pragma unroll
      for (int r = 0; r < 4; r++) {
        int row = m0 + i * 16 + mq * 4 + r;
        if (row < M) C[(size_t)row * N + col] = f2bf(acc[i][j][r] + bcol);
      }
    }
  }
}

// ---------------- fused attention: one wave per edge ----------------
__global__ __launch_bounds__(256) void k_attn(const unsigned short* __restrict__ xlr,
                                              const float* __restrict__ att,
                                              const int* __restrict__ offs,
                                              const int* __restrict__ src_s,
                                              const float* __restrict__ bias,
                                              unsigned short* __restrict__ hout) {
  __shared__ float red[4][8][68];
  __shared__ float reds[4][8];
  int n = blockIdx.x;
  int wave = threadIdx.x >> 6, lane = threadIdx.x & 63;
  int h = lane >> 3, k = lane & 7;
  int c = h * 64 + k * 8;
  int s0 = offs[n], s1 = offs[n + 1];

  uint4 uxr = *(const uint4*)(xlr + (size_t)n * XLR_W + HID + c);
  float xr[8];
  xr[0] = asf(uxr.x << 16); xr[1] = asf(uxr.x & 0xFFFF0000u);
  xr[2] = asf(uxr.y << 16); xr[3] = asf(uxr.y & 0xFFFF0000u);
  xr[4] = asf(uxr.z << 16); xr[5] = asf(uxr.z & 0xFFFF0000u);
  xr[6] = asf(uxr.w << 16); xr[7] = asf(uxr.w & 0xFFFF0000u);
  float at[8];
  {
    const float4* ap = (const float4*)(att + c);
    float4 a0 = ap[0], a1 = ap[1];
    at[0] = a0.x; at[1] = a0.y; at[2] = a0.z; at[3] = a0.w;
    at[4] = a1.x; at[5] = a1.y; at[6] = a1.z; at[7] = a1.w;
  }

  float acc[8] = {0.f, 0.f, 0.f, 0.f, 0.f, 0.f, 0.f, 0.f};
  float sum = 0.0f;

  int i = s0 + wave;
  uint4 u_cur = make_uint4(0, 0, 0, 0);
  if (i < s1) {
    int s = src_s[i];
    u_cur = *(const uint4*)(xlr + (size_t)s * XLR_W + c);
  }
  int nx = i + 4;
  for (; i < s1; i += 4) {
    uint4 u = u_cur;
    if (nx < s1) {
      int s = src_s[nx];
      u_cur = *(const uint4*)(xlr + (size_t)s * XLR_W + c);
    }
    nx += 4;

    float xl[8];
    xl[0] = asf(u.x << 16); xl[1] = asf(u.x & 0xFFFF0000u);
    xl[2] = asf(u.y << 16); xl[3] = asf(u.y & 0xFFFF0000u);
    xl[4] = asf(u.z << 16); xl[5] = asf(u.z & 0xFFFF0000u);
    xl[6] = asf(u.w << 16); xl[7] = asf(u.w & 0xFFFF0000u);

    float l = 0.0f;
#pragma unroll
    for (int j = 0; j < 8; j++) {
      float v = xl[j] + xr[j];
      v = fmaf(0.4f, fabsf(v), 0.6f * v);  // LeakyReLU(0.2)
      l = fmaf(v, at[j], l);
    }
    l += __shfl_xor(l, 1, 64);
    l += __shfl_xor(l, 2, 64);
    l += __shfl_xor(l, 4, 64);

    float p = __expf(l);
    sum += p;
#pragma unroll
    for (int j = 0; j < 8; j++) acc[j] = fmaf(p, xl[j], acc[j]);
  }

#pragma unroll
  for (int j = 0; j < 8; j++) red[wave][h][k * 8 + j] = acc[j];
  if (k == 0) reds[wave][h] = sum;
  __syncthreads();

  int t = threadIdx.x;
  int cc = t * 2;
  int hh = cc >> 6, off = cc & 63;
  float a0 = red[0][hh][off] + red[1][hh][off] + red[2][hh][off] + red[3][hh][off];
  float a1 = red[0][hh][off + 1] + red[1][hh][off + 1] + red[2][hh][off + 1] + red[3][hh][off + 1];
  float sm = reds[0][hh] + reds[1][hh] + reds[2][hh] + reds[3][hh];
  float di = 1.0f / (sm + 1e-16f);
  float o_a = a0 * di + bias[cc];
  float o_b = a1 * di + bias[cc + 1];
  o_a = o_a > 0.0f ? o_a : (__expf(o_a) - 1.0f);
  o_b = o_b > 0.0f ? o_b : (__expf(o_b) - 1.0f);
  unsigned int up = (unsigned int)f2bf(o_a) | ((unsigned int)f2bf(o_b) << 16);
  *(unsigned int*)(hout + (size_t)n * HID + cc) = up;
}

// ---------------- pool (partial sums, 4 blocks per graph) ----------------
__device__ __forceinline__ int lower_bound(const int* __restrict__ a, int n, int key) {
  int lo = 0, hi = n;
  while (lo < hi) { int mid = (lo + hi) >> 1; if (a[mid] < key) lo = mid + 1; else hi = mid; }
  return lo;
}

__global__ __launch_bounds__(256) void k_pool(const unsigned short* __restrict__ h,
                                              const int* __restrict__ batch,
                                              float* __restrict__ part) {
  int g = blockIdx.x, p = blockIdx.y, t = threadIdx.x;
  int start = lower_bound(batch, NN, g);
  int end = lower_bound(batch, NN, g + 1);
  int cntq = (end - start + 3) >> 2;
  int lo = start + p * cntq;
  int hi = lo + cntq; if (hi > end) hi = end;
  int c = t * 2;
  float a0 = 0.0f, a1 = 0.0f;
  for (int n = lo; n < hi; n++) {
    unsigned int u = *(const unsigned int*)(h + (size_t)n * HID + c);
    a0 += asf(u << 16);
    a1 += asf(u & 0xFFFF0000u);
  }
  float* dstp = part + ((size_t)g * 4 + p) * HID + c;
  dstp[0] = a0;
  dstp[1] = a1;
}

// ---------------- BN + FC fused ----------------
__global__ __launch_bounds__(256) void k_fc(const float* __restrict__ part,
                                            const float* __restrict__ gamma,
                                            const float* __restrict__ beta,
                                            const float* __restrict__ mean,
                                            const float* __restrict__ var,
                                            const float* __restrict__ Wfc,
                                            const float* __restrict__ bfc,
                                            float* __restrict__ out) {
  __shared__ float xsm[512];
  int g = blockIdx.x, t = threadIdx.x;
  for (int c = t; c < HID; c += 256) {
    float s = part[((size_t)g * 4 + 0) * HID + c] + part[((size_t)g * 4 + 1) * HID + c]
            + part[((size_t)g * 4 + 2) * HID + c] + part[((size_t)g * 4 + 3) * HID + c];
    xsm[c] = (s - mean[c]) * rsqrtf(var[c] + 1e-5f) * gamma[c] + beta[c];
  }
  __syncthreads();
  float acc = bfc[t];
#pragma unroll 8
  for (int k = 0; k < 512; k++) acc += xsm[k] * Wfc[k * 256 + t];
  out[g * 256 + t] = acc;
}

extern "C" void kernel_launch(void* const* d_in, const int* in_sizes, int n_in,
                              void* d_out, int out_size, void* d_ws, size_t ws_size,
                              hipStream_t stream) {
  const float* x     = (const float*)d_in[0];
  const int* ei      = (const int*)d_in[1];
  const int* batch   = (const int*)d_in[2];
  const float* Wl0   = (const float*)d_in[3];
  const float* bl0   = (const float*)d_in[4];
  const float* Wr0   = (const float*)d_in[5];
  const float* br0   = (const float*)d_in[6];
  const float* att0  = (const float*)d_in[7];
  const float* bias0 = (const float*)d_in[8];
  const float* Wl1   = (const float*)d_in[9];
  const float* bl1   = (const float*)d_in[10];
  const float* Wr1   = (const float*)d_in[11];
  const float* br1   = (const float*)d_in[12];
  const float* att1  = (const float*)d_in[13];
  const float* bias1 = (const float*)d_in[14];
  const float* gamma = (const float*)d_in[15];
  const float* beta  = (const float*)d_in[16];
  const float* mean  = (const float*)d_in[17];
  const float* var   = (const float*)d_in[18];
  const float* Wfc   = (const float*)d_in[19];
  const float* bfc   = (const float*)d_in[20];

  const int* src = ei;
  const int* dst = ei + NE;

  char* w = (char*)d_ws;
  size_t off = 0;
  auto alloc = [&](size_t bytes) -> void* {
    void* p = w + off;
    off += (bytes + 255) & ~(size_t)255;
    return p;
  };
  int* deg            = (int*)alloc((size_t)NN * 4);
  int* offs           = (int*)alloc((size_t)(NN + 1) * 4);
  int* woff           = (int*)alloc((size_t)NN * 4);
  int* src_s          = (int*)alloc((size_t)NE * 4);
  int* btot           = (int*)alloc((size_t)32 * 4);
  unsigned short* xb  = (unsigned short*)alloc((size_t)NN * 256 * 2);
  unsigned short* xlr = (unsigned short*)alloc((size_t)NN * XLR_W * 2);
  unsigned short* hb  = (unsigned short*)alloc((size_t)NN * HID * 2);
  unsigned short* wt0 = (unsigned short*)alloc((size_t)XLR_W * 256 * 2);
  unsigned short* wt1 = (unsigned short*)alloc((size_t)XLR_W * HID * 2);
  float* bcat0        = (float*)alloc((size_t)XLR_W * 4);
  float* bcat1        = (float*)alloc((size_t)XLR_W * 4);
  float* part         = (float*)alloc((size_t)NG * 4 * HID * 4);

  const int NB = (NN + 1023) / 1024;  // 20

  k_prep<<<8151, 256, 0, stream>>>(x, xb, Wl0, bl0, Wr0, br0, wt0, bcat0,
                                   Wl1, bl1, Wr1, br1, wt1, bcat1, deg);
  k_hist<<<(NE + 255) / 256, 256, 0, stream>>>(dst, deg, NE);
  k_scan1<<<NB, 1024, 0, stream>>>(deg, offs, btot, NN);
  k_scan3<<<NB, 1024, 0, stream>>>(offs, btot, woff, NN, NB);
  k_scatter<<<(NE + 255) / 256, 256, 0, stream>>>(src, dst, woff, src_s, NE);

  // 313 m-tiles x 16 n-tiles = 5008 waves = 1252 blocks
  const int GB = ((NN + 63) / 64) * 16 / 4;

  // layer 0
  k_gemm<<<GB, 256, 0, stream>>>(xb, wt0, bcat0, xlr, NN, XLR_W, 256);
  k_attn<<<NN, 256, 0, stream>>>(xlr, att0, offs, src_s, bias0, hb);

  // layer 1
  k_gemm<<<GB, 256, 0, stream>>>(hb, wt1, bcat1, xlr, NN, XLR_W, 512);
  k_attn<<<NN, 256, 0, stream>>>(xlr, att1, offs, src_s, bias1, hb);

  k_pool<<<dim3(NG, 4), 256, 0, stream>>>(hb, batch, part);
  k_fc<<<NG, 256, 0, stream>>>(part, gamma, beta, mean, var, Wfc, bfc, (float*)d_out);
}

// Round 12
// 324.926 us; speedup vs baseline: 1.1884x; 1.1884x over previous
//
#include <hip/hip_runtime.h>
#include <hip/hip_bf16.h>
#include <cstdint>

#define NN 20000
#define NE 200000
#define NG 128
#define HID 512
#define XLR_W 1024

typedef __attribute__((ext_vector_type(4))) float f32x4;
typedef __attribute__((ext_vector_type(8))) short s16x8;

__device__ __forceinline__ float bf2f(unsigned short u) {
  union { unsigned int i; float f; } v; v.i = ((unsigned int)u) << 16; return v.f;
}
__device__ __forceinline__ unsigned short f2bf(float f) {
  union { float f; unsigned int i; } v; v.f = f;
  unsigned int i = v.i + 0x7FFFu + ((v.i >> 16) & 1u);
  return (unsigned short)(i >> 16);
}
__device__ __forceinline__ float asf(unsigned int u) {
  union { unsigned int i; float f; } v; v.i = u; return v.f;
}

#define GLOAD16(gp, lp)                                                        \
  __builtin_amdgcn_global_load_lds(                                            \
      (const __attribute__((address_space(1))) unsigned int*)(gp),             \
      (__attribute__((address_space(3))) unsigned int*)(lp), 16, 0, 0)

// ---------------- fused prep: zero deg + cast x + pack W0 + pack W1 ----------------
__global__ __launch_bounds__(256) void k_prep(const float* __restrict__ x,
                                              unsigned short* __restrict__ xb,
                                              const float* __restrict__ Wl0, const float* __restrict__ bl0,
                                              const float* __restrict__ Wr0, const float* __restrict__ br0,
                                              unsigned short* __restrict__ wt0, float* __restrict__ bcat0,
                                              const float* __restrict__ Wl1, const float* __restrict__ bl1,
                                              const float* __restrict__ Wr1, const float* __restrict__ br1,
                                              unsigned short* __restrict__ wt1, float* __restrict__ bcat1,
                                              int* __restrict__ deg) {
  int b = blockIdx.x, t = threadIdx.x;
  if (b < 79) {
    int i = b * 256 + t;
    if (i < NN) deg[i] = 0;
  } else if (b < 5079) {
    int i = (b - 79) * 256 + t;
    float4 v = ((const float4*)x)[i];
    ushort4 o;
    o.x = f2bf(v.x); o.y = f2bf(v.y); o.z = f2bf(v.z); o.w = f2bf(v.w);
    ((ushort4*)xb)[i] = o;
  } else if (b < 6103) {
    int id = (b - 5079) * 256 + t;
    int nrow = id >> 8, k = id & 255;
    float v = (nrow < HID) ? Wl0[k * HID + nrow] : Wr0[k * HID + (nrow - HID)];
    wt0[id] = f2bf(v);
    if (id < XLR_W) bcat0[id] = (id < HID) ? bl0[id] : br0[id - HID];
  } else {
    int id = (b - 6103) * 256 + t;
    int nrow = id >> 9, k = id & 511;
    float v = (nrow < HID) ? Wl1[k * HID + nrow] : Wr1[k * HID + (nrow - HID)];
    wt1[id] = f2bf(v);
    if (id < XLR_W) bcat1[id] = (id < HID) ? bl1[id] : br1[id - HID];
  }
}

// ---------------- CSR build ----------------
__global__ void k_hist(const int* __restrict__ dst, int* __restrict__ deg, int E) {
  int i = blockIdx.x * blockDim.x + threadIdx.x;
  if (i < E) atomicAdd(&deg[dst[i]], 1);
}

__global__ __launch_bounds__(1024) void k_scan1(const int* __restrict__ deg,
                                                int* __restrict__ offs,
                                                int* __restrict__ btot, int n) {
  __shared__ int wsum[16];
  int t = threadIdx.x;
  int wid = t >> 6, lane = t & 63;
  int i = blockIdx.x * 1024 + t;
  int v = (i < n) ? deg[i] : 0;
  int s = v;
#pragma unroll
  for (int off = 1; off < 64; off <<= 1) {
    int x = __shfl_up(s, off, 64);
    if (lane >= off) s += x;
  }
  if (lane == 63) wsum[wid] = s;
  __syncthreads();
  if (wid == 0) {
    int ws = (lane < 16) ? wsum[lane] : 0;
#pragma unroll
    for (int off = 1; off < 16; off <<= 1) {
      int x = __shfl_up(ws, off, 64);
      if (lane >= off) ws += x;
    }
    if (lane < 16) wsum[lane] = ws;
  }
  __syncthreads();
  int ex = s - v + (wid ? wsum[wid - 1] : 0);
  if (i < n) offs[i] = ex;
  if (t == 1023) btot[blockIdx.x] = ex + v;
}

__global__ __launch_bounds__(1024) void k_scan3(int* __restrict__ offs,
                                                const int* __restrict__ btot,
                                                int* __restrict__ woff, int n, int nb) {
  __shared__ int sbofs;
  int t = threadIdx.x;
  if (t < 64) {
    int v = (t < nb) ? btot[t] : 0;
    int s = v;
#pragma unroll
    for (int off = 1; off < 64; off <<= 1) {
      int x = __shfl_up(s, off, 64);
      if (t >= off) s += x;
    }
    if (t == (int)blockIdx.x) sbofs = s - v;
    if (blockIdx.x == (unsigned)(nb - 1) && t == nb - 1) offs[n] = s;
  }
  __syncthreads();
  int add = sbofs;
  int i = blockIdx.x * 1024 + t;
  if (i < n) {
    int v = offs[i] + add;
    offs[i] = v;
    woff[i] = v;
  }
}

__global__ void k_scatter(const int* __restrict__ src, const int* __restrict__ dst,
                          int* __restrict__ woff, int* __restrict__ src_s, int E) {
  int i = blockIdx.x * blockDim.x + threadIdx.x;
  if (i < E) {
    int d = dst[i];
    int pos = atomicAdd(&woff[d], 1);
    src_s[pos] = src[i];
  }
}

// ---------------- GEMM: glds staging, BK=64 as two [128][32] planes (half the barriers) ----------------
#define BM 128
#define BN 128
#define PLN 4096  // elems per plane: 128*32

__global__ __launch_bounds__(256) void k_gemm(const unsigned short* __restrict__ A,
                                              const unsigned short* __restrict__ Bt,
                                              const float* __restrict__ bias,
                                              unsigned short* __restrict__ C,
                                              int M, int N, int K) {
  __shared__ __align__(16) unsigned short As[2 * PLN];
  __shared__ __align__(16) unsigned short Bs[2 * PLN];
  int m0 = blockIdx.y * BM, n0 = blockIdx.x * BN;
  int t = threadIdx.x;
  int wave = t >> 6, lane = t & 63;
  int wm = (wave >> 1) * 64, wn = (wave & 1) * 64;
  int ml = lane & 15, mq = lane >> 4;
  int lr = lane >> 2;          // 0..15: row within a 16-row chunk
  int lq = (lane & 3) * 8;     // elem offset within a 32-elem plane row

  f32x4 acc[4][4];
#pragma unroll
  for (int i = 0; i < 4; i++)
#pragma unroll
    for (int j = 0; j < 4; j++) acc[i][j] = (f32x4)0.0f;

  // staging: 4 chunks each for A and B, chunk idx = p*2+h (plane p, half h)
  const unsigned short* gA[4];
  const unsigned short* gB[4];
  unsigned short* lA[4];
  unsigned short* lB[4];
#pragma unroll
  for (int p = 0; p < 2; p++)
#pragma unroll
    for (int h = 0; h < 2; h++) {
      int idx = p * 2 + h;
      int arow = m0 + wave * 32 + h * 16 + lr; if (arow > M - 1) arow = M - 1;
      gA[idx] = A + (size_t)arow * K + p * 32 + lq;
      gB[idx] = Bt + (size_t)(n0 + wave * 32 + h * 16 + lr) * K + p * 32 + lq;
      lA[idx] = &As[p * PLN + (wave * 32 + h * 16) * 32];
      lB[idx] = &Bs[p * PLN + (wave * 32 + h * 16) * 32];
    }

  int T = K >> 6;  // K/64
  for (int tt = 0; tt < T; tt++) {
#pragma unroll
    for (int idx = 0; idx < 4; idx++) {
      GLOAD16(gA[idx], lA[idx]);
      GLOAD16(gB[idx], lB[idx]);
      gA[idx] += 64; gB[idx] += 64;
    }
    __syncthreads();
#pragma unroll
    for (int kq = 0; kq < 2; kq++) {
      s16x8 af[4], bfr[4];
#pragma unroll
      for (int i = 0; i < 4; i++)
        af[i] = *(const s16x8*)(&As[kq * PLN + (wm + i * 16 + ml) * 32 + mq * 8]);
#pragma unroll
      for (int j = 0; j < 4; j++)
        bfr[j] = *(const s16x8*)(&Bs[kq * PLN + (wn + j * 16 + ml) * 32 + mq * 8]);
#pragma unroll
      for (int i = 0; i < 4; i++)
#pragma unroll
        for (int j = 0; j < 4; j++)
          acc[i][j] = __builtin_amdgcn_mfma_f32_16x16x32_bf16(af[i], bfr[j], acc[i][j], 0, 0, 0);
    }
    __syncthreads();
  }

#pragma unroll
  for (int i = 0; i < 4; i++) {
#pragma unroll
    for (int j = 0; j < 4; j++) {
      int col = n0 + wn + j * 16 + ml;
      float bcol = bias[col];
#pragma unroll
      for (int r = 0; r < 4; r++) {
        int row = m0 + wm + i * 16 + mq * 4 + r;
        if (row < M) C[(size_t)row * N + col] = f2bf(acc[i][j][r] + bcol);
      }
    }
  }
}

// ---------------- fused attention: one wave per edge ----------------
__global__ __launch_bounds__(256) void k_attn(const unsigned short* __restrict__ xlr,
                                              const float* __restrict__ att,
                                              const int* __restrict__ offs,
                                              const int* __restrict__ src_s,
                                              const float* __restrict__ bias,
                                              unsigned short* __restrict__ hout) {
  __shared__ float red[4][8][68];
  __shared__ float reds[4][8];
  int n = blockIdx.x;
  int wave = threadIdx.x >> 6, lane = threadIdx.x & 63;
  int h = lane >> 3, k = lane & 7;
  int c = h * 64 + k * 8;
  int s0 = offs[n], s1 = offs[n + 1];

  uint4 uxr = *(const uint4*)(xlr + (size_t)n * XLR_W + HID + c);
  float xr[8];
  xr[0] = asf(uxr.x << 16); xr[1] = asf(uxr.x & 0xFFFF0000u);
  xr[2] = asf(uxr.y << 16); xr[3] = asf(uxr.y & 0xFFFF0000u);
  xr[4] = asf(uxr.z << 16); xr[5] = asf(uxr.z & 0xFFFF0000u);
  xr[6] = asf(uxr.w << 16); xr[7] = asf(uxr.w & 0xFFFF0000u);
  float at[8];
  {
    const float4* ap = (const float4*)(att + c);
    float4 a0 = ap[0], a1 = ap[1];
    at[0] = a0.x; at[1] = a0.y; at[2] = a0.z; at[3] = a0.w;
    at[4] = a1.x; at[5] = a1.y; at[6] = a1.z; at[7] = a1.w;
  }

  float acc[8] = {0.f, 0.f, 0.f, 0.f, 0.f, 0.f, 0.f, 0.f};
  float sum = 0.0f;

  int i = s0 + wave;
  uint4 u_cur = make_uint4(0, 0, 0, 0);
  if (i < s1) {
    int s = src_s[i];
    u_cur = *(const uint4*)(xlr + (size_t)s * XLR_W + c);
  }
  int nx = i + 4;
  for (; i < s1; i += 4) {
    uint4 u = u_cur;
    if (nx < s1) {
      int s = src_s[nx];
      u_cur = *(const uint4*)(xlr + (size_t)s * XLR_W + c);
    }
    nx += 4;

    float xl[8];
    xl[0] = asf(u.x << 16); xl[1] = asf(u.x & 0xFFFF0000u);
    xl[2] = asf(u.y << 16); xl[3] = asf(u.y & 0xFFFF0000u);
    xl[4] = asf(u.z << 16); xl[5] = asf(u.z & 0xFFFF0000u);
    xl[6] = asf(u.w << 16); xl[7] = asf(u.w & 0xFFFF0000u);

    float l = 0.0f;
#pragma unroll
    for (int j = 0; j < 8; j++) {
      float v = xl[j] + xr[j];
      v = fmaf(0.4f, fabsf(v), 0.6f * v);  // LeakyReLU(0.2)
      l = fmaf(v, at[j], l);
    }
    l += __shfl_xor(l, 1, 64);
    l += __shfl_xor(l, 2, 64);
    l += __shfl_xor(l, 4, 64);

    float p = __expf(l);
    sum += p;
#pragma unroll
    for (int j = 0; j < 8; j++) acc[j] = fmaf(p, xl[j], acc[j]);
  }

#pragma unroll
  for (int j = 0; j < 8; j++) red[wave][h][k * 8 + j] = acc[j];
  if (k == 0) reds[wave][h] = sum;
  __syncthreads();

  int t = threadIdx.x;
  int cc = t * 2;
  int hh = cc >> 6, off = cc & 63;
  float a0 = red[0][hh][off] + red[1][hh][off] + red[2][hh][off] + red[3][hh][off];
  float a1 = red[0][hh][off + 1] + red[1][hh][off + 1] + red[2][hh][off + 1] + red[3][hh][off + 1];
  float sm = reds[0][hh] + reds[1][hh] + reds[2][hh] + reds[3][hh];
  float di = 1.0f / (sm + 1e-16f);
  float o_a = a0 * di + bias[cc];
  float o_b = a1 * di + bias[cc + 1];
  o_a = o_a > 0.0f ? o_a : (__expf(o_a) - 1.0f);
  o_b = o_b > 0.0f ? o_b : (__expf(o_b) - 1.0f);
  unsigned int up = (unsigned int)f2bf(o_a) | ((unsigned int)f2bf(o_b) << 16);
  *(unsigned int*)(hout + (size_t)n * HID + cc) = up;
}

// ---------------- pool (partial sums, 4 blocks per graph) ----------------
__device__ __forceinline__ int lower_bound(const int* __restrict__ a, int n, int key) {
  int lo = 0, hi = n;
  while (lo < hi) { int mid = (lo + hi) >> 1; if (a[mid] < key) lo = mid + 1; else hi = mid; }
  return lo;
}

__global__ __launch_bounds__(256) void k_pool(const unsigned short* __restrict__ h,
                                              const int* __restrict__ batch,
                                              float* __restrict__ part) {
  int g = blockIdx.x, p = blockIdx.y, t = threadIdx.x;
  int start = lower_bound(batch, NN, g);
  int end = lower_bound(batch, NN, g + 1);
  int cntq = (end - start + 3) >> 2;
  int lo = start + p * cntq;
  int hi = lo + cntq; if (hi > end) hi = end;
  int c = t * 2;
  float a0 = 0.0f, a1 = 0.0f;
  for (int n = lo; n < hi; n++) {
    unsigned int u = *(const unsigned int*)(h + (size_t)n * HID + c);
    a0 += asf(u << 16);
    a1 += asf(u & 0xFFFF0000u);
  }
  float* dstp = part + ((size_t)g * 4 + p) * HID + c;
  dstp[0] = a0;
  dstp[1] = a1;
}

// ---------------- BN + FC fused ----------------
__global__ __launch_bounds__(256) void k_fc(const float* __restrict__ part,
                                            const float* __restrict__ gamma,
                                            const float* __restrict__ beta,
                                            const float* __restrict__ mean,
                                            const float* __restrict__ var,
                                            const float* __restrict__ Wfc,
                                            const float* __restrict__ bfc,
                                            float* __restrict__ out) {
  __shared__ float xsm[512];
  int g = blockIdx.x, t = threadIdx.x;
  for (int c = t; c < HID; c += 256) {
    float s = part[((size_t)g * 4 + 0) * HID + c] + part[((size_t)g * 4 + 1) * HID + c]
            + part[((size_t)g * 4 + 2) * HID + c] + part[((size_t)g * 4 + 3) * HID + c];
    xsm[c] = (s - mean[c]) * rsqrtf(var[c] + 1e-5f) * gamma[c] + beta[c];
  }
  __syncthreads();
  float acc = bfc[t];
#pragma unroll 8
  for (int k = 0; k < 512; k++) acc += xsm[k] * Wfc[k * 256 + t];
  out[g * 256 + t] = acc;
}

extern "C" void kernel_launch(void* const* d_in, const int* in_sizes, int n_in,
                              void* d_out, int out_size, void* d_ws, size_t ws_size,
                              hipStream_t stream) {
  const float* x     = (const float*)d_in[0];
  const int* ei      = (const int*)d_in[1];
  const int* batch   = (const int*)d_in[2];
  const float* Wl0   = (const float*)d_in[3];
  const float* bl0   = (const float*)d_in[4];
  const float* Wr0   = (const float*)d_in[5];
  const float* br0   = (const float*)d_in[6];
  const float* att0  = (const float*)d_in[7];
  const float* bias0 = (const float*)d_in[8];
  const float* Wl1   = (const float*)d_in[9];
  const float* bl1   = (const float*)d_in[10];
  const float* Wr1   = (const float*)d_in[11];
  const float* br1   = (const float*)d_in[12];
  const float* att1  = (const float*)d_in[13];
  const float* bias1 = (const float*)d_in[14];
  const float* gamma = (const float*)d_in[15];
  const float* beta  = (const float*)d_in[16];
  const float* mean  = (const float*)d_in[17];
  const float* var   = (const float*)d_in[18];
  const float* Wfc   = (const float*)d_in[19];
  const float* bfc   = (const float*)d_in[20];

  const int* src = ei;
  const int* dst = ei + NE;

  char* w = (char*)d_ws;
  size_t off = 0;
  auto alloc = [&](size_t bytes) -> void* {
    void* p = w + off;
    off += (bytes + 255) & ~(size_t)255;
    return p;
  };
  int* deg            = (int*)alloc((size_t)NN * 4);
  int* offs           = (int*)alloc((size_t)(NN + 1) * 4);
  int* woff           = (int*)alloc((size_t)NN * 4);
  int* src_s          = (int*)alloc((size_t)NE * 4);
  int* btot           = (int*)alloc((size_t)32 * 4);
  unsigned short* xb  = (unsigned short*)alloc((size_t)NN * 256 * 2);
  unsigned short* xlr = (unsigned short*)alloc((size_t)NN * XLR_W * 2);
  unsigned short* hb  = (unsigned short*)alloc((size_t)NN * HID * 2);
  unsigned short* wt0 = (unsigned short*)alloc((size_t)XLR_W * 256 * 2);
  unsigned short* wt1 = (unsigned short*)alloc((size_t)XLR_W * HID * 2);
  float* bcat0        = (float*)alloc((size_t)XLR_W * 4);
  float* bcat1        = (float*)alloc((size_t)XLR_W * 4);
  float* part         = (float*)alloc((size_t)NG * 4 * HID * 4);

  const int NB = (NN + 1023) / 1024;  // 20

  k_prep<<<8151, 256, 0, stream>>>(x, xb, Wl0, bl0, Wr0, br0, wt0, bcat0,
                                   Wl1, bl1, Wr1, br1, wt1, bcat1, deg);
  k_hist<<<(NE + 255) / 256, 256, 0, stream>>>(dst, deg, NE);
  k_scan1<<<NB, 1024, 0, stream>>>(deg, offs, btot, NN);
  k_scan3<<<NB, 1024, 0, stream>>>(offs, btot, woff, NN, NB);
  k_scatter<<<(NE + 255) / 256, 256, 0, stream>>>(src, dst, woff, src_s, NE);

  // layer 0
  k_gemm<<<dim3(XLR_W / BN, (NN + BM - 1) / BM), 256, 0, stream>>>(xb, wt0, bcat0, xlr, NN, XLR_W, 256);
  k_attn<<<NN, 256, 0, stream>>>(xlr, att0, offs, src_s, bias0, hb);

  // layer 1
  k_gemm<<<dim3(XLR_W / BN, (NN + BM - 1) / BM), 256, 0, stream>>>(hb, wt1, bcat1, xlr, NN, XLR_W, 512);
  k_attn<<<NN, 256, 0, stream>>>(xlr, att1, offs, src_s, bias1, hb);

  k_pool<<<dim3(NG, 4), 256, 0, stream>>>(hb, batch, part);
  k_fc<<<NG, 256, 0, stream>>>(part, gamma, beta, mean, var, Wfc, bfc, (float*)d_out);
}

// Round 13
// 315.093 us; speedup vs baseline: 1.2255x; 1.0312x over previous
//
#include <hip/hip_runtime.h>
#include <hip/hip_bf16.h>
#include <cstdint>

#define NN 20000
#define NE 200000
#define NG 128
#define HID 512
#define XLR_W 1024

typedef __attribute__((ext_vector_type(4))) float f32x4;
typedef __attribute__((ext_vector_type(8))) short s16x8;

__device__ __forceinline__ float bf2f(unsigned short u) {
  union { unsigned int i; float f; } v; v.i = ((unsigned int)u) << 16; return v.f;
}
__device__ __forceinline__ unsigned short f2bf(float f) {
  union { float f; unsigned int i; } v; v.f = f;
  unsigned int i = v.i + 0x7FFFu + ((v.i >> 16) & 1u);
  return (unsigned short)(i >> 16);
}
__device__ __forceinline__ float asf(unsigned int u) {
  union { unsigned int i; float f; } v; v.i = u; return v.f;
}

#define GLOAD16(gp, lp)                                                        \
  __builtin_amdgcn_global_load_lds(                                            \
      (const __attribute__((address_space(1))) unsigned int*)(gp),             \
      (__attribute__((address_space(3))) unsigned int*)(lp), 16, 0, 0)

// ---------------- fused prep: zero deg + cast x + pack W0 + pack W1 ----------------
__global__ __launch_bounds__(256) void k_prep(const float* __restrict__ x,
                                              unsigned short* __restrict__ xb,
                                              const float* __restrict__ Wl0, const float* __restrict__ bl0,
                                              const float* __restrict__ Wr0, const float* __restrict__ br0,
                                              unsigned short* __restrict__ wt0, float* __restrict__ bcat0,
                                              const float* __restrict__ Wl1, const float* __restrict__ bl1,
                                              const float* __restrict__ Wr1, const float* __restrict__ br1,
                                              unsigned short* __restrict__ wt1, float* __restrict__ bcat1,
                                              int* __restrict__ deg) {
  int b = blockIdx.x, t = threadIdx.x;
  if (b < 79) {
    int i = b * 256 + t;
    if (i < NN) deg[i] = 0;
  } else if (b < 5079) {
    int i = (b - 79) * 256 + t;
    float4 v = ((const float4*)x)[i];
    ushort4 o;
    o.x = f2bf(v.x); o.y = f2bf(v.y); o.z = f2bf(v.z); o.w = f2bf(v.w);
    ((ushort4*)xb)[i] = o;
  } else if (b < 6103) {
    int id = (b - 5079) * 256 + t;
    int nrow = id >> 8, k = id & 255;
    float v = (nrow < HID) ? Wl0[k * HID + nrow] : Wr0[k * HID + (nrow - HID)];
    wt0[id] = f2bf(v);
    if (id < XLR_W) bcat0[id] = (id < HID) ? bl0[id] : br0[id - HID];
  } else {
    int id = (b - 6103) * 256 + t;
    int nrow = id >> 9, k = id & 511;
    float v = (nrow < HID) ? Wl1[k * HID + nrow] : Wr1[k * HID + (nrow - HID)];
    wt1[id] = f2bf(v);
    if (id < XLR_W) bcat1[id] = (id < HID) ? bl1[id] : br1[id - HID];
  }
}

// ---------------- CSR build ----------------
__global__ void k_hist(const int* __restrict__ dst, int* __restrict__ deg, int E) {
  int i = blockIdx.x * blockDim.x + threadIdx.x;
  if (i < E) atomicAdd(&deg[dst[i]], 1);
}

__global__ __launch_bounds__(1024) void k_scan1(const int* __restrict__ deg,
                                                int* __restrict__ offs,
                                                int* __restrict__ btot, int n) {
  __shared__ int wsum[16];
  int t = threadIdx.x;
  int wid = t >> 6, lane = t & 63;
  int i = blockIdx.x * 1024 + t;
  int v = (i < n) ? deg[i] : 0;
  int s = v;
#pragma unroll
  for (int off = 1; off < 64; off <<= 1) {
    int x = __shfl_up(s, off, 64);
    if (lane >= off) s += x;
  }
  if (lane == 63) wsum[wid] = s;
  __syncthreads();
  if (wid == 0) {
    int ws = (lane < 16) ? wsum[lane] : 0;
#pragma unroll
    for (int off = 1; off < 16; off <<= 1) {
      int x = __shfl_up(ws, off, 64);
      if (lane >= off) ws += x;
    }
    if (lane < 16) wsum[lane] = ws;
  }
  __syncthreads();
  int ex = s - v + (wid ? wsum[wid - 1] : 0);
  if (i < n) offs[i] = ex;
  if (t == 1023) btot[blockIdx.x] = ex + v;
}

__global__ __launch_bounds__(1024) void k_scan3(int* __restrict__ offs,
                                                const int* __restrict__ btot,
                                                int* __restrict__ woff, int n, int nb) {
  __shared__ int sbofs;
  int t = threadIdx.x;
  if (t < 64) {
    int v = (t < nb) ? btot[t] : 0;
    int s = v;
#pragma unroll
    for (int off = 1; off < 64; off <<= 1) {
      int x = __shfl_up(s, off, 64);
      if (t >= off) s += x;
    }
    if (t == (int)blockIdx.x) sbofs = s - v;
    if (blockIdx.x == (unsigned)(nb - 1) && t == nb - 1) offs[n] = s;
  }
  __syncthreads();
  int add = sbofs;
  int i = blockIdx.x * 1024 + t;
  if (i < n) {
    int v = offs[i] + add;
    offs[i] = v;
    woff[i] = v;
  }
}

__global__ void k_scatter(const int* __restrict__ src, const int* __restrict__ dst,
                          int* __restrict__ woff, int* __restrict__ src_s, int E) {
  int i = blockIdx.x * blockDim.x + threadIdx.x;
  if (i < E) {
    int d = dst[i];
    int pos = atomicAdd(&woff[d], 1);
    src_s[pos] = src[i];
  }
}

// ---------------- GEMM: glds + BK=64 two planes + XOR-swizzled LDS + XCD-aware remap ----------------
// Swizzle: LDS slot (row r, quarter q_l) holds global quarter q_g = q_l ^ ((r>>1)&3).
// Read side: global quarter mq lives at q_l = mq ^ ((ml>>1)&3) -> 4-bank groups hit
// exactly 2x per 16 lanes = conflict-free. Store side: glds lane->slot mapping is
// contiguous (conflict-free); per-lane gptr permuted within each 64B line (coalescing kept).
#define BM 128
#define BN 128
#define PLN 4096  // elems per plane: 128*32

__global__ __launch_bounds__(256) void k_gemm(const unsigned short* __restrict__ A,
                                              const unsigned short* __restrict__ Bt,
                                              const float* __restrict__ bias,
                                              unsigned short* __restrict__ C,
                                              int M, int N, int K, int nby) {
  // XCD-aware remap (assumes round-robin XCD = linear_id % 8): all 8 n-strips of one
  // m-row share an XCD L2 -> A fetched once per L2 instead of 8x.
  int L = blockIdx.x;
  int by = (L & 7) | ((L >> 6) << 3);
  int bx = (L >> 3) & 7;
  if (by >= nby) return;
  int m0 = by * BM, n0 = bx * BN;

  __shared__ __align__(16) unsigned short As[2 * PLN];
  __shared__ __align__(16) unsigned short Bs[2 * PLN];
  int t = threadIdx.x;
  int wave = t >> 6, lane = t & 63;
  int wm = (wave >> 1) * 64, wn = (wave & 1) * 64;
  int ml = lane & 15, mq = lane >> 4;
  int lr = lane >> 2;                              // row within 16-row chunk
  int qg = (lane & 3) ^ ((lane >> 3) & 3);         // swizzled global quarter for staging
  int lq = qg * 8;                                 // elem offset in 32-elem plane row

  f32x4 acc[4][4];
#pragma unroll
  for (int i = 0; i < 4; i++)
#pragma unroll
    for (int j = 0; j < 4; j++) acc[i][j] = (f32x4)0.0f;

  const unsigned short* gA[4];
  const unsigned short* gB[4];
  unsigned short* lA[4];
  unsigned short* lB[4];
#pragma unroll
  for (int p = 0; p < 2; p++)
#pragma unroll
    for (int h = 0; h < 2; h++) {
      int idx = p * 2 + h;
      int arow = m0 + wave * 32 + h * 16 + lr; if (arow > M - 1) arow = M - 1;
      gA[idx] = A + (size_t)arow * K + p * 32 + lq;
      gB[idx] = Bt + (size_t)(n0 + wave * 32 + h * 16 + lr) * K + p * 32 + lq;
      lA[idx] = &As[p * PLN + (wave * 32 + h * 16) * 32];
      lB[idx] = &Bs[p * PLN + (wave * 32 + h * 16) * 32];
    }

  // read-side swizzled quarter (wave-constant per lane)
  int qr = (mq ^ ((ml >> 1) & 3)) * 8;

  int T = K >> 6;  // K/64
  for (int tt = 0; tt < T; tt++) {
#pragma unroll
    for (int idx = 0; idx < 4; idx++) {
      GLOAD16(gA[idx], lA[idx]);
      GLOAD16(gB[idx], lB[idx]);
      gA[idx] += 64; gB[idx] += 64;
    }
    __syncthreads();
#pragma unroll
    for (int kq = 0; kq < 2; kq++) {
      s16x8 af[4], bfr[4];
#pragma unroll
      for (int i = 0; i < 4; i++)
        af[i] = *(const s16x8*)(&As[kq * PLN + (wm + i * 16 + ml) * 32 + qr]);
#pragma unroll
      for (int j = 0; j < 4; j++)
        bfr[j] = *(const s16x8*)(&Bs[kq * PLN + (wn + j * 16 + ml) * 32 + qr]);
#pragma unroll
      for (int i = 0; i < 4; i++)
#pragma unroll
        for (int j = 0; j < 4; j++)
          acc[i][j] = __builtin_amdgcn_mfma_f32_16x16x32_bf16(af[i], bfr[j], acc[i][j], 0, 0, 0);
    }
    __syncthreads();
  }

#pragma unroll
  for (int i = 0; i < 4; i++) {
#pragma unroll
    for (int j = 0; j < 4; j++) {
      int col = n0 + wn + j * 16 + ml;
      float bcol = bias[col];
#pragma unroll
      for (int r = 0; r < 4; r++) {
        int row = m0 + wm + i * 16 + mq * 4 + r;
        if (row < M) C[(size_t)row * N + col] = f2bf(acc[i][j][r] + bcol);
      }
    }
  }
}

// ---------------- fused attention: one wave per edge ----------------
__global__ __launch_bounds__(256) void k_attn(const unsigned short* __restrict__ xlr,
                                              const float* __restrict__ att,
                                              const int* __restrict__ offs,
                                              const int* __restrict__ src_s,
                                              const float* __restrict__ bias,
                                              unsigned short* __restrict__ hout) {
  __shared__ float red[4][8][68];
  __shared__ float reds[4][8];
  int n = blockIdx.x;
  int wave = threadIdx.x >> 6, lane = threadIdx.x & 63;
  int h = lane >> 3, k = lane & 7;
  int c = h * 64 + k * 8;
  int s0 = offs[n], s1 = offs[n + 1];

  uint4 uxr = *(const uint4*)(xlr + (size_t)n * XLR_W + HID + c);
  float xr[8];
  xr[0] = asf(uxr.x << 16); xr[1] = asf(uxr.x & 0xFFFF0000u);
  xr[2] = asf(uxr.y << 16); xr[3] = asf(uxr.y & 0xFFFF0000u);
  xr[4] = asf(uxr.z << 16); xr[5] = asf(uxr.z & 0xFFFF0000u);
  xr[6] = asf(uxr.w << 16); xr[7] = asf(uxr.w & 0xFFFF0000u);
  float at[8];
  {
    const float4* ap = (const float4*)(att + c);
    float4 a0 = ap[0], a1 = ap[1];
    at[0] = a0.x; at[1] = a0.y; at[2] = a0.z; at[3] = a0.w;
    at[4] = a1.x; at[5] = a1.y; at[6] = a1.z; at[7] = a1.w;
  }

  float acc[8] = {0.f, 0.f, 0.f, 0.f, 0.f, 0.f, 0.f, 0.f};
  float sum = 0.0f;

  int i = s0 + wave;
  uint4 u_cur = make_uint4(0, 0, 0, 0);
  if (i < s1) {
    int s = src_s[i];
    u_cur = *(const uint4*)(xlr + (size_t)s * XLR_W + c);
  }
  int nx = i + 4;
  for (; i < s1; i += 4) {
    uint4 u = u_cur;
    if (nx < s1) {
      int s = src_s[nx];
      u_cur = *(const uint4*)(xlr + (size_t)s * XLR_W + c);
    }
    nx += 4;

    float xl[8];
    xl[0] = asf(u.x << 16); xl[1] = asf(u.x & 0xFFFF0000u);
    xl[2] = asf(u.y << 16); xl[3] = asf(u.y & 0xFFFF0000u);
    xl[4] = asf(u.z << 16); xl[5] = asf(u.z & 0xFFFF0000u);
    xl[6] = asf(u.w << 16); xl[7] = asf(u.w & 0xFFFF0000u);

    float l = 0.0f;
#pragma unroll
    for (int j = 0; j < 8; j++) {
      float v = xl[j] + xr[j];
      v = fmaf(0.4f, fabsf(v), 0.6f * v);  // LeakyReLU(0.2)
      l = fmaf(v, at[j], l);
    }
    l += __shfl_xor(l, 1, 64);
    l += __shfl_xor(l, 2, 64);
    l += __shfl_xor(l, 4, 64);

    float p = __expf(l);
    sum += p;
#pragma unroll
    for (int j = 0; j < 8; j++) acc[j] = fmaf(p, xl[j], acc[j]);
  }

#pragma unroll
  for (int j = 0; j < 8; j++) red[wave][h][k * 8 + j] = acc[j];
  if (k == 0) reds[wave][h] = sum;
  __syncthreads();

  int t = threadIdx.x;
  int cc = t * 2;
  int hh = cc >> 6, off = cc & 63;
  float a0 = red[0][hh][off] + red[1][hh][off] + red[2][hh][off] + red[3][hh][off];
  float a1 = red[0][hh][off + 1] + red[1][hh][off + 1] + red[2][hh][off + 1] + red[3][hh][off + 1];
  float sm = reds[0][hh] + reds[1][hh] + reds[2][hh] + reds[3][hh];
  float di = 1.0f / (sm + 1e-16f);
  float o_a = a0 * di + bias[cc];
  float o_b = a1 * di + bias[cc + 1];
  o_a = o_a > 0.0f ? o_a : (__expf(o_a) - 1.0f);
  o_b = o_b > 0.0f ? o_b : (__expf(o_b) - 1.0f);
  unsigned int up = (unsigned int)f2bf(o_a) | ((unsigned int)f2bf(o_b) << 16);
  *(unsigned int*)(hout + (size_t)n * HID + cc) = up;
}

// ---------------- pool (partial sums, 4 blocks per graph) ----------------
__device__ __forceinline__ int lower_bound(const int* __restrict__ a, int n, int key) {
  int lo = 0, hi = n;
  while (lo < hi) { int mid = (lo + hi) >> 1; if (a[mid] < key) lo = mid + 1; else hi = mid; }
  return lo;
}

__global__ __launch_bounds__(256) void k_pool(const unsigned short* __restrict__ h,
                                              const int* __restrict__ batch,
                                              float* __restrict__ part) {
  int g = blockIdx.x, p = blockIdx.y, t = threadIdx.x;
  int start = lower_bound(batch, NN, g);
  int end = lower_bound(batch, NN, g + 1);
  int cntq = (end - start + 3) >> 2;
  int lo = start + p * cntq;
  int hi = lo + cntq; if (hi > end) hi = end;
  int c = t * 2;
  float a0 = 0.0f, a1 = 0.0f;
  for (int n = lo; n < hi; n++) {
    unsigned int u = *(const unsigned int*)(h + (size_t)n * HID + c);
    a0 += asf(u << 16);
    a1 += asf(u & 0xFFFF0000u);
  }
  float* dstp = part + ((size_t)g * 4 + p) * HID + c;
  dstp[0] = a0;
  dstp[1] = a1;
}

// ---------------- BN + FC fused ----------------
__global__ __launch_bounds__(256) void k_fc(const float* __restrict__ part,
                                            const float* __restrict__ gamma,
                                            const float* __restrict__ beta,
                                            const float* __restrict__ mean,
                                            const float* __restrict__ var,
                                            const float* __restrict__ Wfc,
                                            const float* __restrict__ bfc,
                                            float* __restrict__ out) {
  __shared__ float xsm[512];
  int g = blockIdx.x, t = threadIdx.x;
  for (int c = t; c < HID; c += 256) {
    float s = part[((size_t)g * 4 + 0) * HID + c] + part[((size_t)g * 4 + 1) * HID + c]
            + part[((size_t)g * 4 + 2) * HID + c] + part[((size_t)g * 4 + 3) * HID + c];
    xsm[c] = (s - mean[c]) * rsqrtf(var[c] + 1e-5f) * gamma[c] + beta[c];
  }
  __syncthreads();
  float acc = bfc[t];
#pragma unroll 8
  for (int k = 0; k < 512; k++) acc += xsm[k] * Wfc[k * 256 + t];
  out[g * 256 + t] = acc;
}

extern "C" void kernel_launch(void* const* d_in, const int* in_sizes, int n_in,
                              void* d_out, int out_size, void* d_ws, size_t ws_size,
                              hipStream_t stream) {
  const float* x     = (const float*)d_in[0];
  const int* ei      = (const int*)d_in[1];
  const int* batch   = (const int*)d_in[2];
  const float* Wl0   = (const float*)d_in[3];
  const float* bl0   = (const float*)d_in[4];
  const float* Wr0   = (const float*)d_in[5];
  const float* br0   = (const float*)d_in[6];
  const float* att0  = (const float*)d_in[7];
  const float* bias0 = (const float*)d_in[8];
  const float* Wl1   = (const float*)d_in[9];
  const float* bl1   = (const float*)d_in[10];
  const float* Wr1   = (const float*)d_in[11];
  const float* br1   = (const float*)d_in[12];
  const float* att1  = (const float*)d_in[13];
  const float* bias1 = (const float*)d_in[14];
  const float* gamma = (const float*)d_in[15];
  const float* beta  = (const float*)d_in[16];
  const float* mean  = (const float*)d_in[17];
  const float* var   = (const float*)d_in[18];
  const float* Wfc   = (const float*)d_in[19];
  const float* bfc   = (const float*)d_in[20];

  const int* src = ei;
  const int* dst = ei + NE;

  char* w = (char*)d_ws;
  size_t off = 0;
  auto alloc = [&](size_t bytes) -> void* {
    void* p = w + off;
    off += (bytes + 255) & ~(size_t)255;
    return p;
  };
  int* deg            = (int*)alloc((size_t)NN * 4);
  int* offs           = (int*)alloc((size_t)(NN + 1) * 4);
  int* woff           = (int*)alloc((size_t)NN * 4);
  int* src_s          = (int*)alloc((size_t)NE * 4);
  int* btot           = (int*)alloc((size_t)32 * 4);
  unsigned short* xb  = (unsigned short*)alloc((size_t)NN * 256 * 2);
  unsigned short* xlr = (unsigned short*)alloc((size_t)NN * XLR_W * 2);
  unsigned short* hb  = (unsigned short*)alloc((size_t)NN * HID * 2);
  unsigned short* wt0 = (unsigned short*)alloc((size_t)XLR_W * 256 * 2);
  unsigned short* wt1 = (unsigned short*)alloc((size_t)XLR_W * HID * 2);
  float* bcat0        = (float*)alloc((size_t)XLR_W * 4);
  float* bcat1        = (float*)alloc((size_t)XLR_W * 4);
  float* part         = (float*)alloc((size_t)NG * 4 * HID * 4);

  const int NB = (NN + 1023) / 1024;       // 20
  const int NBY = (NN + BM - 1) / BM;      // 157
  const int GRID = 64 * ((NBY + 7) / 8);   // 1280

  k_prep<<<8151, 256, 0, stream>>>(x, xb, Wl0, bl0, Wr0, br0, wt0, bcat0,
                                   Wl1, bl1, Wr1, br1, wt1, bcat1, deg);
  k_hist<<<(NE + 255) / 256, 256, 0, stream>>>(dst, deg, NE);
  k_scan1<<<NB, 1024, 0, stream>>>(deg, offs, btot, NN);
  k_scan3<<<NB, 1024, 0, stream>>>(offs, btot, woff, NN, NB);
  k_scatter<<<(NE + 255) / 256, 256, 0, stream>>>(src, dst, woff, src_s, NE);

  // layer 0
  k_gemm<<<GRID, 256, 0, stream>>>(xb, wt0, bcat0, xlr, NN, XLR_W, 256, NBY);
  k_attn<<<NN, 256, 0, stream>>>(xlr, att0, offs, src_s, bias0, hb);

  // layer 1
  k_gemm<<<GRID, 256, 0, stream>>>(hb, wt1, bcat1, xlr, NN, XLR_W, 512, NBY);
  k_attn<<<NN, 256, 0, stream>>>(xlr, att1, offs, src_s, bias1, hb);

  k_pool<<<dim3(NG, 4), 256, 0, stream>>>(hb, batch, part);
  k_fc<<<NG, 256, 0, stream>>>(part, gamma, beta, mean, var, Wfc, bfc, (float*)d_out);
}